// Round 7
// baseline (194.213 us; speedup 1.0000x reference)
//
#include <hip/hip_runtime.h>
#include <hip/hip_bf16.h>
#include <stdint.h>

namespace gat {
constexpr int NB   = 16;
constexpr int NN   = 512;
constexpr int FIN  = 256;
constexpr int FOUT = 256;
constexpr int H    = 8;
constexpr int NE   = 50;
constexpr float L2E  = 1.4426950408889634f;   // log2(e)
constexpr float MASKB = -192.0f;              // masked emb entry: exp2 -> ~5e-11
constexpr float RBIAS = 0.00281502f;          // counters bf16-truncation bias
constexpr unsigned long long MAGIC = 0x13579BDF02468ACEull; // non-repeating-byte token
}
using namespace gat;

typedef __attribute__((ext_vector_type(8))) short short8;
typedef __attribute__((ext_vector_type(4))) float f32x4;

__device__ __forceinline__ unsigned pk_bf16(unsigned ulo, unsigned uhi) {
  return __builtin_amdgcn_perm(uhi, ulo, 0x07060302u);   // take high halves (truncate)
}
__device__ __forceinline__ unsigned pk2f(float a, float b) {
  return pk_bf16(__float_as_uint(a) + 0x8000u, __float_as_uint(b) + 0x8000u);
}
__device__ __forceinline__ unsigned short bf1(float a) {
  return (unsigned short)((__float_as_uint(a) + 0x8000u) >> 16);
}

// ======= k_pg: prew (blocks 0..256) + GEMM (blocks 257..768) in ONE dispatch =======
// Deadlock-proof handshake: 769 blocks x 256 thr at <=8.4KB LDS / <=128 VGPR -> >=8
// blocks/CU -> ALL 769 co-resident regardless of dispatch order. Producers publish
// 64-bit magic tokens (workspace is poisoned, so zero-init is unavailable); consumers
// poll with agent-scope atomic loads, then __threadfence() (L2 inv) before reading WbTa.
__global__ __launch_bounds__(256, 4) void k_pg(
    const float* __restrict__ x, const float* __restrict__ Wm,
    const float* __restrict__ a1, const float* __restrict__ a2,
    unsigned short* __restrict__ WbTa, unsigned short* __restrict__ WhT,
    float* __restrict__ s1T, float* __restrict__ s2T,
    unsigned long long* __restrict__ flags)
{
  const int t = threadIdx.x;

  if (blockIdx.x < 257) {   // ---------- prew role (r5 k_prew verbatim) ----------
    const int blk = blockIdx.x;
    if (blk < 256) {
      WbTa[t * FIN + blk] = bf1(Wm[blk * FOUT + t]);
    } else {
      const int k = t;
      const float* wr = Wm + (size_t)k * FOUT;
      #pragma unroll
      for (int h = 0; h < H; ++h) {
        float v1 = 0.f, v2 = 0.f;
        #pragma unroll
        for (int d = 0; d < 32; ++d) {
          const float wv = wr[h * 32 + d];
          v1 += wv * a1[d];
          v2 += wv * a2[d];
        }
        WbTa[(256 + h) * FIN + k] = bf1(v1);
        WbTa[(264 + h) * FIN + k] = bf1(v2);
      }
    }
    __threadfence();           // per-thread: drain own stores + L2 writeback
    __syncthreads();
    if (t == 0)
      __hip_atomic_store(&flags[blk], MAGIC, __ATOMIC_RELEASE, __HIP_MEMORY_SCOPE_AGENT);
    return;
  }

  // ---------- GEMM role (r5 k_gp verbatim + handshake) ----------
  __shared__ alignas(16) unsigned short xS[16 * 264];
  const int row0 = (blockIdx.x - 257) * 16;
  {
    const int r  = t >> 4;
    const int kb = (t & 15) * 16;
    const float4* xg = (const float4*)(x + (size_t)(row0 + r) * FIN + kb);
    const float4 v0 = xg[0], v1 = xg[1], v2 = xg[2], v3 = xg[3];
    uint4 o0, o1;
    o0.x = pk2f(v0.x, v0.y); o0.y = pk2f(v0.z, v0.w);
    o0.z = pk2f(v1.x, v1.y); o0.w = pk2f(v1.z, v1.w);
    o1.x = pk2f(v2.x, v2.y); o1.y = pk2f(v2.z, v2.w);
    o1.z = pk2f(v3.x, v3.y); o1.w = pk2f(v3.z, v3.w);
    *(uint4*)&xS[r * 264 + kb]     = o0;
    *(uint4*)&xS[r * 264 + kb + 8] = o1;
  }

  // wait for all 257 producers (thread t polls slot t; thread 0 also slot 256)
  for (;;) {
    unsigned long long v =
        __hip_atomic_load(&flags[t], __ATOMIC_RELAXED, __HIP_MEMORY_SCOPE_AGENT);
    int ok = (v == MAGIC);
    if (t == 0) {
      unsigned long long v2 =
          __hip_atomic_load(&flags[256], __ATOMIC_RELAXED, __HIP_MEMORY_SCOPE_AGENT);
      ok &= (v2 == MAGIC);
    }
    if (__syncthreads_and(ok)) break;   // barrier also covers the xS staging
    __builtin_amdgcn_s_sleep(8);
  }
  __threadfence();   // acquire side: invalidate stale (poisoned) L2 lines before WbTa reads

  const int w    = t >> 6;
  const int L    = t & 63;
  const int nn   = L & 15;
  const int quad = L >> 4;
  const unsigned short* wb = WbTa + (size_t)(w * 64 + nn) * FIN + quad * 8;
  const unsigned short* wa = WbTa + (size_t)(256 + nn) * FIN + quad * 8;
  const unsigned short* xp = &xS[nn * 264 + quad * 8];

  f32x4 acc0 = {0.f,0.f,0.f,0.f}, acc1 = {0.f,0.f,0.f,0.f};
  f32x4 acc2 = {0.f,0.f,0.f,0.f}, acc3 = {0.f,0.f,0.f,0.f};
  f32x4 accA = {0.f,0.f,0.f,0.f};

  #pragma unroll
  for (int kc = 0; kc < 8; ++kc) {
    const int k0 = kc * 32;
    const short8 A  = *(const short8*)(xp + k0);
    const short8 B0 = *(const short8*)(wb + k0);
    const short8 B1 = *(const short8*)(wb + 16 * FIN + k0);
    const short8 B2 = *(const short8*)(wb + 32 * FIN + k0);
    const short8 B3 = *(const short8*)(wb + 48 * FIN + k0);
    acc0 = __builtin_amdgcn_mfma_f32_16x16x32_bf16(A, B0, acc0, 0, 0, 0);
    acc1 = __builtin_amdgcn_mfma_f32_16x16x32_bf16(A, B1, acc1, 0, 0, 0);
    acc2 = __builtin_amdgcn_mfma_f32_16x16x32_bf16(A, B2, acc2, 0, 0, 0);
    acc3 = __builtin_amdgcn_mfma_f32_16x16x32_bf16(A, B3, acc3, 0, 0, 0);
    if (w == 3) {
      const short8 BA = *(const short8*)(wa + k0);
      accA = __builtin_amdgcn_mfma_f32_16x16x32_bf16(A, BA, accA, 0, 0, 0);
    }
  }

  const int b     = row0 >> 9;
  const int node0 = (row0 & 511) + quad * 4;
  f32x4 accs[4] = {acc0, acc1, acc2, acc3};
  #pragma unroll
  for (int ft = 0; ft < 4; ++ft) {
    const int f = w * 64 + ft * 16 + nn;
    uint2 o;
    o.x = pk2f(accs[ft][0], accs[ft][1]);
    o.y = pk2f(accs[ft][2], accs[ft][3]);
    *(uint2*)(WhT + (size_t)((b * 8 + (f >> 5)) * 32 + (f & 31)) * 512 + node0) = o;
  }
  if (w == 3) {
    float4 sv;
    sv.x = accA[0] * L2E; sv.y = accA[1] * L2E;
    sv.z = accA[2] * L2E; sv.w = accA[3] * L2E;
    float* dst = (nn < 8) ? (s1T + (size_t)(b * 8 + nn) * 512 + node0)
                          : (s2T + (size_t)(b * 8 + (nn - 8)) * 512 + node0);
    *(float4*)dst = sv;
  }
}

// ---------------- k_attn (r5 passing version, byte-identical) ----------------
__global__ __launch_bounds__(512, 2) void k_attn(
    const int* __restrict__ adj, const int* __restrict__ ety,
    const float* __restrict__ s1T, const float* __restrict__ s2T,
    const unsigned short* __restrict__ WhT, const float* __restrict__ emb,
    const float* __restrict__ gam, const float* __restrict__ bet,
    float* __restrict__ out)
{
  __shared__ float2 lnS[16 * 4];
  __shared__ float  s2S[8 * 512];
  __shared__ float  redS[256 * 18];
  __shared__ alignas(16) unsigned int codesS[16 * 132];   // 528 B row stride

  const int t    = threadIdx.x;
  const int b    = blockIdx.x >> 5;
  const int i0   = (blockIdx.x & 31) * 16;
  const int W    = t >> 6;
  const int w    = W & 3;
  const int jh   = W >> 2;
  const int L    = t & 63;
  const int i    = L & 15;
  const int quad = L >> 4;
  const int h0   = w, h1 = w + 4;

  {
    const float4* sg = (const float4*)(s2T + (size_t)b * 8 * 512);
    float4* ss = (float4*)s2S;
    ss[t]       = sg[t];
    ss[t + 512] = sg[t + 512];
  }
  { // fused pack: adj/ety slice -> codesS
    const int r = t >> 5, c = t & 31;
    const size_t base = ((size_t)(b * NN + i0 + r) << 9) + c * 16;
    const int4* ap = (const int4*)(adj + base);
    const int4* ep = (const int4*)(ety + base);
    unsigned o[4];
    #pragma unroll
    for (int g = 0; g < 4; ++g) {
      const int4 a = ap[g];
      const int4 e = ep[g];
      o[g] = (unsigned)(e.x | (a.x << 6))
           | ((unsigned)(e.y | (a.y << 6)) << 8)
           | ((unsigned)(e.z | (a.z << 6)) << 16)
           | ((unsigned)(e.w | (a.w << 6)) << 24);
    }
    uint4 v; v.x = o[0]; v.y = o[1]; v.z = o[2]; v.w = o[3];
    *(uint4*)&codesS[r * 132 + c * 4] = v;
  }

  // register-resident emb table: lane L holds entry for type==L (L<50), per head pair
  float tabx = 0.f, taby = 0.f;
  if (L < NE) {
    tabx = emb[L * H + h0] * L2E + RBIAS;
    taby = emb[L * H + h1] * L2E + RBIAS;
  }
  const int txi = __builtin_bit_cast(int, tabx);
  const int tyi = __builtin_bit_cast(int, taby);

  const int row   = b * NN + i0 + i;
  const int jbase = jh * 256;
  const float si0 = s1T[(size_t)(b * 8 + h0) * 512 + i0 + i];
  const float si1 = s1T[(size_t)(b * 8 + h1) * 512 + i0 + i];
  const unsigned short* wt00 = WhT + (size_t)((b * 8 + h0) * 32 + i)      * 512;
  const unsigned short* wt01 = WhT + (size_t)((b * 8 + h0) * 32 + 16 + i) * 512;
  const unsigned short* wt10 = WhT + (size_t)((b * 8 + h1) * 32 + i)      * 512;
  const unsigned short* wt11 = WhT + (size_t)((b * 8 + h1) * 32 + 16 + i) * 512;

  f32x4 acc00 = {0.f,0.f,0.f,0.f}, acc01 = {0.f,0.f,0.f,0.f};
  f32x4 acc10 = {0.f,0.f,0.f,0.f}, acc11 = {0.f,0.f,0.f,0.f};
  f32x4 accL0 = {0.f,0.f,0.f,0.f}, accL1 = {0.f,0.f,0.f,0.f};
  const short one_bf = (short)0x3F80;
  const short8 ONES = {one_bf, one_bf, one_bf, one_bf, one_bf, one_bf, one_bf, one_bf};

  const float*  s2p0 = s2S + h0 * 512;
  const float*  s2p1 = s2S + h1 * 512;

  // A-frag pipeline: kc=0
  const int ja0 = jbase + quad * 8;
  short8 nA00 = *(const short8*)(wt00 + ja0);
  short8 nA01 = *(const short8*)(wt01 + ja0);
  short8 nA10 = *(const short8*)(wt10 + ja0);
  short8 nA11 = *(const short8*)(wt11 + ja0);

  __syncthreads();

  // codes for this thread's (i, jh, quad) from LDS (2-way bank = free)
  uint2 cw[8];
  {
    const unsigned int* cwp = &codesS[i * 132 + (jbase >> 2) + quad * 2];
    #pragma unroll
    for (int kc = 0; kc < 8; ++kc) {
      cw[kc].x = cwp[kc * 8];
      cw[kc].y = cwp[kc * 8 + 1];
    }
  }

  // e-operand pipeline: stage kc=0
  float2 em[8]; float4 sa0, sb0, sa1, sb1;
  {
    sa0 = *(const float4*)&s2p0[ja0];
    sb0 = *(const float4*)&s2p0[ja0 + 4];
    sa1 = *(const float4*)&s2p1[ja0];
    sb1 = *(const float4*)&s2p1[ja0 + 4];
    #pragma unroll
    for (int q = 0; q < 8; ++q) {
      const unsigned cword = (q < 4) ? cw[0].x : cw[0].y;
      const unsigned cb = (cword >> ((q & 3) * 8)) & 0xffu;
      const int ad = (int)((cb & 0x3fu) << 2);
      const float gx = __builtin_bit_cast(float, __builtin_amdgcn_ds_bpermute(ad, txi));
      const float gy = __builtin_bit_cast(float, __builtin_amdgcn_ds_bpermute(ad, tyi));
      em[q].x = (cb >= 64u) ? gx : MASKB;
      em[q].y = (cb >= 64u) ? gy : MASKB;
    }
  }

  #pragma unroll
  for (int kc = 0; kc < 8; ++kc) {
    const int ja = jbase + kc * 32 + quad * 8;
    const short8 A00 = nA00, A01 = nA01, A10 = nA10, A11 = nA11;
    { // prefetch next A-frags (last-iter overread stays inside d_ws)
      const int jn = ja + 32;
      nA00 = *(const short8*)(wt00 + jn);
      nA01 = *(const short8*)(wt01 + jn);
      nA10 = *(const short8*)(wt10 + jn);
      nA11 = *(const short8*)(wt11 + jn);
    }
    // issue next iteration's LDS/crossbar operands NOW
    float2 emn[8]; float4 na0, nb0, na1, nb1;
    if (kc < 7) {
      const int jx = ja + 32;
      na0 = *(const float4*)&s2p0[jx];
      nb0 = *(const float4*)&s2p0[jx + 4];
      na1 = *(const float4*)&s2p1[jx];
      nb1 = *(const float4*)&s2p1[jx + 4];
      #pragma unroll
      for (int q = 0; q < 8; ++q) {
        const unsigned cword = (q < 4) ? cw[kc + 1].x : cw[kc + 1].y;
        const unsigned cb = (cword >> ((q & 3) * 8)) & 0xffu;
        const int ad = (int)((cb & 0x3fu) << 2);
        const float gx = __builtin_bit_cast(float, __builtin_amdgcn_ds_bpermute(ad, txi));
        const float gy = __builtin_bit_cast(float, __builtin_amdgcn_ds_bpermute(ad, tyi));
        emn[q].x = (cb >= 64u) ? gx : MASKB;
        emn[q].y = (cb >= 64u) ? gy : MASKB;
      }
    }

    const float s20[8] = {sa0.x, sa0.y, sa0.z, sa0.w, sb0.x, sb0.y, sb0.z, sb0.w};
    const float s21[8] = {sa1.x, sa1.y, sa1.z, sa1.w, sb1.x, sb1.y, sb1.z, sb1.w};
    unsigned u0[8], u1[8];
    #pragma unroll
    for (int q = 0; q < 8; ++q) {
      float e0 = si0 + s20[q] + em[q].x;
      float e1 = si1 + s21[q] + em[q].y;
      e0 = fmaxf(e0, 0.2f * e0);
      e1 = fmaxf(e1, 0.2f * e1);
      u0[q] = __float_as_uint(exp2f(e0));
      u1[q] = __float_as_uint(exp2f(e1));
    }
    uint4 U0, U1;
    U0.x = pk_bf16(u0[0], u0[1]); U0.y = pk_bf16(u0[2], u0[3]);
    U0.z = pk_bf16(u0[4], u0[5]); U0.w = pk_bf16(u0[6], u0[7]);
    U1.x = pk_bf16(u1[0], u1[1]); U1.y = pk_bf16(u1[2], u1[3]);
    U1.z = pk_bf16(u1[4], u1[5]); U1.w = pk_bf16(u1[6], u1[7]);
    const short8 B0 = __builtin_bit_cast(short8, U0);
    const short8 B1 = __builtin_bit_cast(short8, U1);

    acc00 = __builtin_amdgcn_mfma_f32_16x16x32_bf16(A00, B0, acc00, 0, 0, 0);
    acc01 = __builtin_amdgcn_mfma_f32_16x16x32_bf16(A01, B0, acc01, 0, 0, 0);
    acc10 = __builtin_amdgcn_mfma_f32_16x16x32_bf16(A10, B1, acc10, 0, 0, 0);
    acc11 = __builtin_amdgcn_mfma_f32_16x16x32_bf16(A11, B1, acc11, 0, 0, 0);
    accL0 = __builtin_amdgcn_mfma_f32_16x16x32_bf16(ONES, B0, accL0, 0, 0, 0);
    accL1 = __builtin_amdgcn_mfma_f32_16x16x32_bf16(ONES, B1, accL1, 0, 0, 0);

    if (kc < 7) {
      sa0 = na0; sb0 = nb0; sa1 = na1; sb1 = nb1;
      #pragma unroll
      for (int q = 0; q < 8; ++q) em[q] = emn[q];
    }
  }

  const float l0 = accL0[0];   // D[m][i] = l_i for every m
  const float l1 = accL1[0];

  const int tt = (w << 6) | L;
  if (jh == 1) {
    float* rp = redS + tt * 18;
    rp[0]=acc00[0]; rp[1]=acc00[1]; rp[2]=acc00[2]; rp[3]=acc00[3];
    rp[4]=acc01[0]; rp[5]=acc01[1]; rp[6]=acc01[2]; rp[7]=acc01[3];
    rp[8]=acc10[0]; rp[9]=acc10[1]; rp[10]=acc10[2]; rp[11]=acc10[3];
    rp[12]=acc11[0]; rp[13]=acc11[1]; rp[14]=acc11[2]; rp[15]=acc11[3];
    rp[16]=l0; rp[17]=l1;
  }
  __syncthreads();

  float vals[16]; float mu, rstd;
  if (jh == 0) {
    const float* rp = redS + tt * 18;
    acc00[0]+=rp[0]; acc00[1]+=rp[1]; acc00[2]+=rp[2]; acc00[3]+=rp[3];
    acc01[0]+=rp[4]; acc01[1]+=rp[5]; acc01[2]+=rp[6]; acc01[3]+=rp[7];
    acc10[0]+=rp[8]; acc10[1]+=rp[9]; acc10[2]+=rp[10]; acc10[3]+=rp[11];
    acc11[0]+=rp[12]; acc11[1]+=rp[13]; acc11[2]+=rp[14]; acc11[3]+=rp[15];
    const float inv0 = __builtin_amdgcn_rcpf(l0 + rp[16]);
    const float inv1 = __builtin_amdgcn_rcpf(l1 + rp[17]);
    #pragma unroll
    for (int r = 0; r < 4; ++r) {
      vals[r]      = acc00[r] * inv0;
      vals[4 + r]  = acc01[r] * inv0;
      vals[8 + r]  = acc10[r] * inv1;
      vals[12 + r] = acc11[r] * inv1;
    }
    float s = 0.f, ss = 0.f;
    #pragma unroll
    for (int k = 0; k < 16; ++k) { s += vals[k]; ss += vals[k] * vals[k]; }
    s += __shfl_xor(s, 16); ss += __shfl_xor(ss, 16);
    s += __shfl_xor(s, 32); ss += __shfl_xor(ss, 32);
    if (quad == 0) { float2 v; v.x = s; v.y = ss; lnS[i * 4 + w] = v; }
  }
  __syncthreads();
  if (jh == 1) return;
  {
    float S = 0.f, SS = 0.f;
    #pragma unroll
    for (int ww = 0; ww < 4; ++ww) { const float2 v = lnS[i * 4 + ww]; S += v.x; SS += v.y; }
    mu = S * (1.0f / 256.0f);
    const float var = SS * (1.0f / 256.0f) - mu * mu;
    rstd = rsqrtf(var + 1e-5f);
  }
  const int fb[4] = { h0 * 32 + quad * 4, h0 * 32 + 16 + quad * 4,
                      h1 * 32 + quad * 4, h1 * 32 + 16 + quad * 4 };
  #pragma unroll
  for (int g = 0; g < 4; ++g) {
    const float4 gv = *(const float4*)(gam + fb[g]);
    const float4 bv = *(const float4*)(bet + fb[g]);
    float4 o;
    o.x = (vals[g*4+0] - mu) * rstd * gv.x + bv.x;
    o.y = (vals[g*4+1] - mu) * rstd * gv.y + bv.y;
    o.z = (vals[g*4+2] - mu) * rstd * gv.z + bv.z;
    o.w = (vals[g*4+3] - mu) * rstd * gv.w + bv.w;
    o.x = o.x > 0.f ? o.x : exp2f(o.x * L2E) - 1.f;
    o.y = o.y > 0.f ? o.y : exp2f(o.y * L2E) - 1.f;
    o.z = o.z > 0.f ? o.z : exp2f(o.z * L2E) - 1.f;
    o.w = o.w > 0.f ? o.w : exp2f(o.w * L2E) - 1.f;
    *(float4*)(out + (size_t)row * FOUT + fb[g]) = o;
  }
}

extern "C" void kernel_launch(void* const* d_in, const int* in_sizes, int n_in,
                              void* d_out, int out_size, void* d_ws, size_t ws_size,
                              hipStream_t stream) {
  (void)in_sizes; (void)n_in; (void)out_size; (void)ws_size;
  const float* x   = (const float*)d_in[0];
  const int*   adj = (const int*)  d_in[1];
  const int*   ety = (const int*)  d_in[2];
  const float* Wm  = (const float*)d_in[3];
  const float* a1  = (const float*)d_in[4];
  const float* a2  = (const float*)d_in[5];
  const float* emb = (const float*)d_in[6];
  const float* gam = (const float*)d_in[7];
  const float* bet = (const float*)d_in[8];
  float* out = (float*)d_out;

  unsigned short* WhT  = (unsigned short*)d_ws;             // 16*8*32*512 bf16 = 4 MB
  unsigned short* WbTa = WhT + (size_t)NB * H * 32 * 512;   // 272*256 bf16
  float* s1T  = (float*)(WbTa + (size_t)272 * FIN);         // 16*8*512 fp32 (pre-scaled)
  float* s2T  = s1T + (size_t)NB * H * NN;                  // 16*8*512 fp32 (pre-scaled)
  unsigned long long* flags = (unsigned long long*)(s2T + (size_t)NB * H * NN); // 257 tokens

  k_pg  <<<dim3(769), dim3(256), 0, stream>>>(x, Wm, a1, a2, WbTa, WhT, s1T, s2T, flags);
  k_attn<<<dim3(NB * (NN / 16)), dim3(512), 0, stream>>>(adj, ety, s1T, s2T, WhT, emb, gam, bet, out);
}

// Round 8
// 126.844 us; speedup vs baseline: 1.5311x; 1.5311x over previous
//
#include <hip/hip_runtime.h>
#include <hip/hip_bf16.h>
#include <stdint.h>

namespace gat {
constexpr int NB   = 16;
constexpr int NN   = 512;
constexpr int FIN  = 256;
constexpr int FOUT = 256;
constexpr int H    = 8;
constexpr int NE   = 50;
constexpr float L2E  = 1.4426950408889634f;   // log2(e)
constexpr float MASKB = -192.0f;              // masked emb entry: exp2 -> ~5e-11
constexpr float RBIAS = 0.00281502f;          // counters bf16-truncation bias
}
using namespace gat;

typedef __attribute__((ext_vector_type(8))) short short8;
typedef __attribute__((ext_vector_type(4))) float f32x4;

__device__ __forceinline__ unsigned pk_bf16(unsigned ulo, unsigned uhi) {
  return __builtin_amdgcn_perm(uhi, ulo, 0x07060302u);   // take high halves (truncate)
}
__device__ __forceinline__ unsigned pk2f(float a, float b) {
  return pk_bf16(__float_as_uint(a) + 0x8000u, __float_as_uint(b) + 0x8000u);
}
__device__ __forceinline__ unsigned short bf1(float a) {
  return (unsigned short)((__float_as_uint(a) + 0x8000u) >> 16);
}

// ---------------- k_prew v2: straggler-free (256 blocks) ----------------
// r5's block 256 (aug role) was a 4-wave straggler: ~64 strided load instrs/thread,
// 64 scattered lines each, serializing k_gp behind it. Now block k transposes row k
// (coalesced read, row becomes L1-resident) and threads t<8 compute the (k, h=t)
// a1/a2 dots from the L1-hot row. Same outputs, no straggler.
__global__ __launch_bounds__(256) void k_prew(const float* __restrict__ Wm,
                                              const float* __restrict__ a1,
                                              const float* __restrict__ a2,
                                              unsigned short* __restrict__ WbTa) {
  const int k = blockIdx.x;
  const int t = threadIdx.x;
  const float* wr = Wm + (size_t)k * FOUT;
  WbTa[t * FIN + k] = bf1(wr[t]);
  if (t < H) {
    const int h = t;
    float v1 = 0.f, v2 = 0.f;
    #pragma unroll
    for (int d = 0; d < 32; ++d) {
      const float wv = wr[h * 32 + d];
      v1 += wv * a1[d];
      v2 += wv * a2[d];
    }
    WbTa[(256 + h) * FIN + k] = bf1(v1);
    WbTa[(264 + h) * FIN + k] = bf1(v2);
  }
}

// ---------------- k_gp: GEMM-only (512 blocks) — r5 verbatim ----------------
__global__ __launch_bounds__(256, 4) void k_gp(
    const float* __restrict__ x, const unsigned short* __restrict__ WbTa,
    unsigned short* __restrict__ WhT, float* __restrict__ s1T, float* __restrict__ s2T)
{
  const int t = threadIdx.x;

  __shared__ alignas(16) unsigned short xS[16 * 264];
  const int row0 = blockIdx.x * 16;
  {
    const int r  = t >> 4;
    const int kb = (t & 15) * 16;
    const float4* xg = (const float4*)(x + (size_t)(row0 + r) * FIN + kb);
    const float4 v0 = xg[0], v1 = xg[1], v2 = xg[2], v3 = xg[3];
    uint4 o0, o1;
    o0.x = pk2f(v0.x, v0.y); o0.y = pk2f(v0.z, v0.w);
    o0.z = pk2f(v1.x, v1.y); o0.w = pk2f(v1.z, v1.w);
    o1.x = pk2f(v2.x, v2.y); o1.y = pk2f(v2.z, v2.w);
    o1.z = pk2f(v3.x, v3.y); o1.w = pk2f(v3.z, v3.w);
    *(uint4*)&xS[r * 264 + kb]     = o0;
    *(uint4*)&xS[r * 264 + kb + 8] = o1;
  }
  __syncthreads();

  const int w    = t >> 6;
  const int L    = t & 63;
  const int nn   = L & 15;
  const int quad = L >> 4;
  const unsigned short* wb = WbTa + (size_t)(w * 64 + nn) * FIN + quad * 8;
  const unsigned short* wa = WbTa + (size_t)(256 + nn) * FIN + quad * 8;
  const unsigned short* xp = &xS[nn * 264 + quad * 8];

  f32x4 acc0 = {0.f,0.f,0.f,0.f}, acc1 = {0.f,0.f,0.f,0.f};
  f32x4 acc2 = {0.f,0.f,0.f,0.f}, acc3 = {0.f,0.f,0.f,0.f};
  f32x4 accA = {0.f,0.f,0.f,0.f};

  #pragma unroll
  for (int kc = 0; kc < 8; ++kc) {
    const int k0 = kc * 32;
    const short8 A  = *(const short8*)(xp + k0);
    const short8 B0 = *(const short8*)(wb + k0);
    const short8 B1 = *(const short8*)(wb + 16 * FIN + k0);
    const short8 B2 = *(const short8*)(wb + 32 * FIN + k0);
    const short8 B3 = *(const short8*)(wb + 48 * FIN + k0);
    acc0 = __builtin_amdgcn_mfma_f32_16x16x32_bf16(A, B0, acc0, 0, 0, 0);
    acc1 = __builtin_amdgcn_mfma_f32_16x16x32_bf16(A, B1, acc1, 0, 0, 0);
    acc2 = __builtin_amdgcn_mfma_f32_16x16x32_bf16(A, B2, acc2, 0, 0, 0);
    acc3 = __builtin_amdgcn_mfma_f32_16x16x32_bf16(A, B3, acc3, 0, 0, 0);
    if (w == 3) {
      const short8 BA = *(const short8*)(wa + k0);
      accA = __builtin_amdgcn_mfma_f32_16x16x32_bf16(A, BA, accA, 0, 0, 0);
    }
  }

  const int b     = row0 >> 9;
  const int node0 = (row0 & 511) + quad * 4;
  f32x4 accs[4] = {acc0, acc1, acc2, acc3};
  #pragma unroll
  for (int ft = 0; ft < 4; ++ft) {
    const int f = w * 64 + ft * 16 + nn;
    uint2 o;
    o.x = pk2f(accs[ft][0], accs[ft][1]);
    o.y = pk2f(accs[ft][2], accs[ft][3]);
    *(uint2*)(WhT + (size_t)((b * 8 + (f >> 5)) * 32 + (f & 31)) * 512 + node0) = o;
  }
  if (w == 3) {
    float4 sv;
    sv.x = accA[0] * L2E; sv.y = accA[1] * L2E;
    sv.z = accA[2] * L2E; sv.w = accA[3] * L2E;
    float* dst = (nn < 8) ? (s1T + (size_t)(b * 8 + nn) * 512 + node0)
                          : (s2T + (size_t)(b * 8 + (nn - 8)) * 512 + node0);
    *(float4*)dst = sv;
  }
}

// ---------------- k_attn (r5 passing version, byte-identical) ----------------
__global__ __launch_bounds__(512, 2) void k_attn(
    const int* __restrict__ adj, const int* __restrict__ ety,
    const float* __restrict__ s1T, const float* __restrict__ s2T,
    const unsigned short* __restrict__ WhT, const float* __restrict__ emb,
    const float* __restrict__ gam, const float* __restrict__ bet,
    float* __restrict__ out)
{
  __shared__ float2 lnS[16 * 4];
  __shared__ float  s2S[8 * 512];
  __shared__ float  redS[256 * 18];
  __shared__ alignas(16) unsigned int codesS[16 * 132];   // 528 B row stride

  const int t    = threadIdx.x;
  const int b    = blockIdx.x >> 5;
  const int i0   = (blockIdx.x & 31) * 16;
  const int W    = t >> 6;
  const int w    = W & 3;
  const int jh   = W >> 2;
  const int L    = t & 63;
  const int i    = L & 15;
  const int quad = L >> 4;
  const int h0   = w, h1 = w + 4;

  {
    const float4* sg = (const float4*)(s2T + (size_t)b * 8 * 512);
    float4* ss = (float4*)s2S;
    ss[t]       = sg[t];
    ss[t + 512] = sg[t + 512];
  }
  { // fused pack: adj/ety slice -> codesS
    const int r = t >> 5, c = t & 31;
    const size_t base = ((size_t)(b * NN + i0 + r) << 9) + c * 16;
    const int4* ap = (const int4*)(adj + base);
    const int4* ep = (const int4*)(ety + base);
    unsigned o[4];
    #pragma unroll
    for (int g = 0; g < 4; ++g) {
      const int4 a = ap[g];
      const int4 e = ep[g];
      o[g] = (unsigned)(e.x | (a.x << 6))
           | ((unsigned)(e.y | (a.y << 6)) << 8)
           | ((unsigned)(e.z | (a.z << 6)) << 16)
           | ((unsigned)(e.w | (a.w << 6)) << 24);
    }
    uint4 v; v.x = o[0]; v.y = o[1]; v.z = o[2]; v.w = o[3];
    *(uint4*)&codesS[r * 132 + c * 4] = v;
  }

  // register-resident emb table: lane L holds entry for type==L (L<50), per head pair
  float tabx = 0.f, taby = 0.f;
  if (L < NE) {
    tabx = emb[L * H + h0] * L2E + RBIAS;
    taby = emb[L * H + h1] * L2E + RBIAS;
  }
  const int txi = __builtin_bit_cast(int, tabx);
  const int tyi = __builtin_bit_cast(int, taby);

  const int row   = b * NN + i0 + i;
  const int jbase = jh * 256;
  const float si0 = s1T[(size_t)(b * 8 + h0) * 512 + i0 + i];
  const float si1 = s1T[(size_t)(b * 8 + h1) * 512 + i0 + i];
  const unsigned short* wt00 = WhT + (size_t)((b * 8 + h0) * 32 + i)      * 512;
  const unsigned short* wt01 = WhT + (size_t)((b * 8 + h0) * 32 + 16 + i) * 512;
  const unsigned short* wt10 = WhT + (size_t)((b * 8 + h1) * 32 + i)      * 512;
  const unsigned short* wt11 = WhT + (size_t)((b * 8 + h1) * 32 + 16 + i) * 512;

  f32x4 acc00 = {0.f,0.f,0.f,0.f}, acc01 = {0.f,0.f,0.f,0.f};
  f32x4 acc10 = {0.f,0.f,0.f,0.f}, acc11 = {0.f,0.f,0.f,0.f};
  f32x4 accL0 = {0.f,0.f,0.f,0.f}, accL1 = {0.f,0.f,0.f,0.f};
  const short one_bf = (short)0x3F80;
  const short8 ONES = {one_bf, one_bf, one_bf, one_bf, one_bf, one_bf, one_bf, one_bf};

  const float*  s2p0 = s2S + h0 * 512;
  const float*  s2p1 = s2S + h1 * 512;

  // A-frag pipeline: kc=0
  const int ja0 = jbase + quad * 8;
  short8 nA00 = *(const short8*)(wt00 + ja0);
  short8 nA01 = *(const short8*)(wt01 + ja0);
  short8 nA10 = *(const short8*)(wt10 + ja0);
  short8 nA11 = *(const short8*)(wt11 + ja0);

  __syncthreads();

  // codes for this thread's (i, jh, quad) from LDS (2-way bank = free)
  uint2 cw[8];
  {
    const unsigned int* cwp = &codesS[i * 132 + (jbase >> 2) + quad * 2];
    #pragma unroll
    for (int kc = 0; kc < 8; ++kc) {
      cw[kc].x = cwp[kc * 8];
      cw[kc].y = cwp[kc * 8 + 1];
    }
  }

  // e-operand pipeline: stage kc=0
  float2 em[8]; float4 sa0, sb0, sa1, sb1;
  {
    sa0 = *(const float4*)&s2p0[ja0];
    sb0 = *(const float4*)&s2p0[ja0 + 4];
    sa1 = *(const float4*)&s2p1[ja0];
    sb1 = *(const float4*)&s2p1[ja0 + 4];
    #pragma unroll
    for (int q = 0; q < 8; ++q) {
      const unsigned cword = (q < 4) ? cw[0].x : cw[0].y;
      const unsigned cb = (cword >> ((q & 3) * 8)) & 0xffu;
      const int ad = (int)((cb & 0x3fu) << 2);
      const float gx = __builtin_bit_cast(float, __builtin_amdgcn_ds_bpermute(ad, txi));
      const float gy = __builtin_bit_cast(float, __builtin_amdgcn_ds_bpermute(ad, tyi));
      em[q].x = (cb >= 64u) ? gx : MASKB;
      em[q].y = (cb >= 64u) ? gy : MASKB;
    }
  }

  #pragma unroll
  for (int kc = 0; kc < 8; ++kc) {
    const int ja = jbase + kc * 32 + quad * 8;
    const short8 A00 = nA00, A01 = nA01, A10 = nA10, A11 = nA11;
    { // prefetch next A-frags (last-iter overread stays inside d_ws)
      const int jn = ja + 32;
      nA00 = *(const short8*)(wt00 + jn);
      nA01 = *(const short8*)(wt01 + jn);
      nA10 = *(const short8*)(wt10 + jn);
      nA11 = *(const short8*)(wt11 + jn);
    }
    // issue next iteration's LDS/crossbar operands NOW
    float2 emn[8]; float4 na0, nb0, na1, nb1;
    if (kc < 7) {
      const int jx = ja + 32;
      na0 = *(const float4*)&s2p0[jx];
      nb0 = *(const float4*)&s2p0[jx + 4];
      na1 = *(const float4*)&s2p1[jx];
      nb1 = *(const float4*)&s2p1[jx + 4];
      #pragma unroll
      for (int q = 0; q < 8; ++q) {
        const unsigned cword = (q < 4) ? cw[kc + 1].x : cw[kc + 1].y;
        const unsigned cb = (cword >> ((q & 3) * 8)) & 0xffu;
        const int ad = (int)((cb & 0x3fu) << 2);
        const float gx = __builtin_bit_cast(float, __builtin_amdgcn_ds_bpermute(ad, txi));
        const float gy = __builtin_bit_cast(float, __builtin_amdgcn_ds_bpermute(ad, tyi));
        emn[q].x = (cb >= 64u) ? gx : MASKB;
        emn[q].y = (cb >= 64u) ? gy : MASKB;
      }
    }

    const float s20[8] = {sa0.x, sa0.y, sa0.z, sa0.w, sb0.x, sb0.y, sb0.z, sb0.w};
    const float s21[8] = {sa1.x, sa1.y, sa1.z, sa1.w, sb1.x, sb1.y, sb1.z, sb1.w};
    unsigned u0[8], u1[8];
    #pragma unroll
    for (int q = 0; q < 8; ++q) {
      float e0 = si0 + s20[q] + em[q].x;
      float e1 = si1 + s21[q] + em[q].y;
      e0 = fmaxf(e0, 0.2f * e0);
      e1 = fmaxf(e1, 0.2f * e1);
      u0[q] = __float_as_uint(exp2f(e0));
      u1[q] = __float_as_uint(exp2f(e1));
    }
    uint4 U0, U1;
    U0.x = pk_bf16(u0[0], u0[1]); U0.y = pk_bf16(u0[2], u0[3]);
    U0.z = pk_bf16(u0[4], u0[5]); U0.w = pk_bf16(u0[6], u0[7]);
    U1.x = pk_bf16(u1[0], u1[1]); U1.y = pk_bf16(u1[2], u1[3]);
    U1.z = pk_bf16(u1[4], u1[5]); U1.w = pk_bf16(u1[6], u1[7]);
    const short8 B0 = __builtin_bit_cast(short8, U0);
    const short8 B1 = __builtin_bit_cast(short8, U1);

    acc00 = __builtin_amdgcn_mfma_f32_16x16x32_bf16(A00, B0, acc00, 0, 0, 0);
    acc01 = __builtin_amdgcn_mfma_f32_16x16x32_bf16(A01, B0, acc01, 0, 0, 0);
    acc10 = __builtin_amdgcn_mfma_f32_16x16x32_bf16(A10, B1, acc10, 0, 0, 0);
    acc11 = __builtin_amdgcn_mfma_f32_16x16x32_bf16(A11, B1, acc11, 0, 0, 0);
    accL0 = __builtin_amdgcn_mfma_f32_16x16x32_bf16(ONES, B0, accL0, 0, 0, 0);
    accL1 = __builtin_amdgcn_mfma_f32_16x16x32_bf16(ONES, B1, accL1, 0, 0, 0);

    if (kc < 7) {
      sa0 = na0; sb0 = nb0; sa1 = na1; sb1 = nb1;
      #pragma unroll
      for (int q = 0; q < 8; ++q) em[q] = emn[q];
    }
  }

  const float l0 = accL0[0];   // D[m][i] = l_i for every m
  const float l1 = accL1[0];

  const int tt = (w << 6) | L;
  if (jh == 1) {
    float* rp = redS + tt * 18;
    rp[0]=acc00[0]; rp[1]=acc00[1]; rp[2]=acc00[2]; rp[3]=acc00[3];
    rp[4]=acc01[0]; rp[5]=acc01[1]; rp[6]=acc01[2]; rp[7]=acc01[3];
    rp[8]=acc10[0]; rp[9]=acc10[1]; rp[10]=acc10[2]; rp[11]=acc10[3];
    rp[12]=acc11[0]; rp[13]=acc11[1]; rp[14]=acc11[2]; rp[15]=acc11[3];
    rp[16]=l0; rp[17]=l1;
  }
  __syncthreads();

  float vals[16]; float mu, rstd;
  if (jh == 0) {
    const float* rp = redS + tt * 18;
    acc00[0]+=rp[0]; acc00[1]+=rp[1]; acc00[2]+=rp[2]; acc00[3]+=rp[3];
    acc01[0]+=rp[4]; acc01[1]+=rp[5]; acc01[2]+=rp[6]; acc01[3]+=rp[7];
    acc10[0]+=rp[8]; acc10[1]+=rp[9]; acc10[2]+=rp[10]; acc10[3]+=rp[11];
    acc11[0]+=rp[12]; acc11[1]+=rp[13]; acc11[2]+=rp[14]; acc11[3]+=rp[15];
    const float inv0 = __builtin_amdgcn_rcpf(l0 + rp[16]);
    const float inv1 = __builtin_amdgcn_rcpf(l1 + rp[17]);
    #pragma unroll
    for (int r = 0; r < 4; ++r) {
      vals[r]      = acc00[r] * inv0;
      vals[4 + r]  = acc01[r] * inv0;
      vals[8 + r]  = acc10[r] * inv1;
      vals[12 + r] = acc11[r] * inv1;
    }
    float s = 0.f, ss = 0.f;
    #pragma unroll
    for (int k = 0; k < 16; ++k) { s += vals[k]; ss += vals[k] * vals[k]; }
    s += __shfl_xor(s, 16); ss += __shfl_xor(ss, 16);
    s += __shfl_xor(s, 32); ss += __shfl_xor(ss, 32);
    if (quad == 0) { float2 v; v.x = s; v.y = ss; lnS[i * 4 + w] = v; }
  }
  __syncthreads();
  if (jh == 1) return;
  {
    float S = 0.f, SS = 0.f;
    #pragma unroll
    for (int ww = 0; ww < 4; ++ww) { const float2 v = lnS[i * 4 + ww]; S += v.x; SS += v.y; }
    mu = S * (1.0f / 256.0f);
    const float var = SS * (1.0f / 256.0f) - mu * mu;
    rstd = rsqrtf(var + 1e-5f);
  }
  const int fb[4] = { h0 * 32 + quad * 4, h0 * 32 + 16 + quad * 4,
                      h1 * 32 + quad * 4, h1 * 32 + 16 + quad * 4 };
  #pragma unroll
  for (int g = 0; g < 4; ++g) {
    const float4 gv = *(const float4*)(gam + fb[g]);
    const float4 bv = *(const float4*)(bet + fb[g]);
    float4 o;
    o.x = (vals[g*4+0] - mu) * rstd * gv.x + bv.x;
    o.y = (vals[g*4+1] - mu) * rstd * gv.y + bv.y;
    o.z = (vals[g*4+2] - mu) * rstd * gv.z + bv.z;
    o.w = (vals[g*4+3] - mu) * rstd * gv.w + bv.w;
    o.x = o.x > 0.f ? o.x : exp2f(o.x * L2E) - 1.f;
    o.y = o.y > 0.f ? o.y : exp2f(o.y * L2E) - 1.f;
    o.z = o.z > 0.f ? o.z : exp2f(o.z * L2E) - 1.f;
    o.w = o.w > 0.f ? o.w : exp2f(o.w * L2E) - 1.f;
    *(float4*)(out + (size_t)row * FOUT + fb[g]) = o;
  }
}

extern "C" void kernel_launch(void* const* d_in, const int* in_sizes, int n_in,
                              void* d_out, int out_size, void* d_ws, size_t ws_size,
                              hipStream_t stream) {
  (void)in_sizes; (void)n_in; (void)out_size; (void)ws_size;
  const float* x   = (const float*)d_in[0];
  const int*   adj = (const int*)  d_in[1];
  const int*   ety = (const int*)  d_in[2];
  const float* Wm  = (const float*)d_in[3];
  const float* a1  = (const float*)d_in[4];
  const float* a2  = (const float*)d_in[5];
  const float* emb = (const float*)d_in[6];
  const float* gam = (const float*)d_in[7];
  const float* bet = (const float*)d_in[8];
  float* out = (float*)d_out;

  unsigned short* WhT  = (unsigned short*)d_ws;             // 16*8*32*512 bf16 = 4 MB
  unsigned short* WbTa = WhT + (size_t)NB * H * 32 * 512;   // 272*256 bf16
  float* s1T  = (float*)(WbTa + (size_t)272 * FIN);         // 16*8*512 fp32 (pre-scaled)
  float* s2T  = s1T + (size_t)NB * H * NN;                  // 16*8*512 fp32 (pre-scaled)

  k_prew<<<dim3(256), dim3(256), 0, stream>>>(Wm, a1, a2, WbTa);
  k_gp  <<<dim3(512), dim3(256), 0, stream>>>(x, WbTa, WhT, s1T, s2T);
  k_attn<<<dim3(NB * (NN / 16)), dim3(512), 0, stream>>>(adj, ety, s1T, s2T, WhT, emb, gam, bet, out);
}

// Round 9
// 126.023 us; speedup vs baseline: 1.5411x; 1.0065x over previous
//
#include <hip/hip_runtime.h>
#include <hip/hip_bf16.h>
#include <stdint.h>

namespace gat {
constexpr int NB   = 16;
constexpr int NN   = 512;
constexpr int FIN  = 256;
constexpr int FOUT = 256;
constexpr int H    = 8;
constexpr int NE   = 50;
constexpr float L2E  = 1.4426950408889634f;   // log2(e)
constexpr float MASKB = -192.0f;              // masked emb entry: exp2 -> ~5e-11
constexpr float RBIAS = 0.00281502f;          // counters bf16-truncation bias
}
using namespace gat;

typedef __attribute__((ext_vector_type(8))) short short8;
typedef __attribute__((ext_vector_type(4))) float f32x4;

__device__ __forceinline__ unsigned pk_bf16(unsigned ulo, unsigned uhi) {
  return __builtin_amdgcn_perm(uhi, ulo, 0x07060302u);   // take high halves (truncate)
}
__device__ __forceinline__ unsigned pk2f(float a, float b) {
  return pk_bf16(__float_as_uint(a) + 0x8000u, __float_as_uint(b) + 0x8000u);
}
__device__ __forceinline__ unsigned short bf1(float a) {
  return (unsigned short)((__float_as_uint(a) + 0x8000u) >> 16);
}

// ---------------- k_prew v2: straggler-free (256 blocks) — r8 verbatim ----------------
__global__ __launch_bounds__(256) void k_prew(const float* __restrict__ Wm,
                                              const float* __restrict__ a1,
                                              const float* __restrict__ a2,
                                              unsigned short* __restrict__ WbTa) {
  const int k = blockIdx.x;
  const int t = threadIdx.x;
  const float* wr = Wm + (size_t)k * FOUT;
  WbTa[t * FIN + k] = bf1(wr[t]);
  if (t < H) {
    const int h = t;
    float v1 = 0.f, v2 = 0.f;
    #pragma unroll
    for (int d = 0; d < 32; ++d) {
      const float wv = wr[h * 32 + d];
      v1 += wv * a1[d];
      v2 += wv * a2[d];
    }
    WbTa[(256 + h) * FIN + k] = bf1(v1);
    WbTa[(264 + h) * FIN + k] = bf1(v2);
  }
}

// ---------------- k_gp v2: GEMM with B-fragment prefetch + 256-VGPR budget ----------------
// r8's (256,4) capped VGPR at 128: the fully-unrolled loop couldn't keep B-fragments in
// flight, so each kc stalled on 4-5 L2/L3-latency WbTa loads (~300cyc exposed x 8 kc).
// (256,2) doubles the budget (grid is 2 blocks/CU anyway -> no occupancy loss) and the
// loop is restructured to explicit prefetch-distance-1 on B (load kc+1 while MFMAing kc).
__global__ __launch_bounds__(256, 2) void k_gp(
    const float* __restrict__ x, const unsigned short* __restrict__ WbTa,
    unsigned short* __restrict__ WhT, float* __restrict__ s1T, float* __restrict__ s2T)
{
  const int t = threadIdx.x;

  __shared__ alignas(16) unsigned short xS[16 * 264];
  const int row0 = blockIdx.x * 16;
  {
    const int r  = t >> 4;
    const int kb = (t & 15) * 16;
    const float4* xg = (const float4*)(x + (size_t)(row0 + r) * FIN + kb);
    const float4 v0 = xg[0], v1 = xg[1], v2 = xg[2], v3 = xg[3];
    uint4 o0, o1;
    o0.x = pk2f(v0.x, v0.y); o0.y = pk2f(v0.z, v0.w);
    o0.z = pk2f(v1.x, v1.y); o0.w = pk2f(v1.z, v1.w);
    o1.x = pk2f(v2.x, v2.y); o1.y = pk2f(v2.z, v2.w);
    o1.z = pk2f(v3.x, v3.y); o1.w = pk2f(v3.z, v3.w);
    *(uint4*)&xS[r * 264 + kb]     = o0;
    *(uint4*)&xS[r * 264 + kb + 8] = o1;
  }

  const int w    = t >> 6;
  const int L    = t & 63;
  const int nn   = L & 15;
  const int quad = L >> 4;
  const unsigned short* wb = WbTa + (size_t)(w * 64 + nn) * FIN + quad * 8;
  const unsigned short* wa = WbTa + (size_t)(256 + nn) * FIN + quad * 8;
  const unsigned short* xp = &xS[nn * 264 + quad * 8];

  // prefetch kc=0 B-fragments (global; issued before the staging barrier)
  short8 nB0 = *(const short8*)(wb);
  short8 nB1 = *(const short8*)(wb + 16 * FIN);
  short8 nB2 = *(const short8*)(wb + 32 * FIN);
  short8 nB3 = *(const short8*)(wb + 48 * FIN);
  short8 nBA = {};
  if (w == 3) nBA = *(const short8*)(wa);

  __syncthreads();

  f32x4 acc0 = {0.f,0.f,0.f,0.f}, acc1 = {0.f,0.f,0.f,0.f};
  f32x4 acc2 = {0.f,0.f,0.f,0.f}, acc3 = {0.f,0.f,0.f,0.f};
  f32x4 accA = {0.f,0.f,0.f,0.f};

  #pragma unroll
  for (int kc = 0; kc < 8; ++kc) {
    const int k0 = kc * 32;
    const short8 A  = *(const short8*)(xp + k0);   // LDS, fast
    const short8 B0 = nB0, B1 = nB1, B2 = nB2, B3 = nB3, BA = nBA;
    if (kc < 7) {   // issue next kc's B-fragments NOW (latency hides under MFMAs)
      const int kn = k0 + 32;
      nB0 = *(const short8*)(wb + kn);
      nB1 = *(const short8*)(wb + 16 * FIN + kn);
      nB2 = *(const short8*)(wb + 32 * FIN + kn);
      nB3 = *(const short8*)(wb + 48 * FIN + kn);
      if (w == 3) nBA = *(const short8*)(wa + kn);
    }
    acc0 = __builtin_amdgcn_mfma_f32_16x16x32_bf16(A, B0, acc0, 0, 0, 0);
    acc1 = __builtin_amdgcn_mfma_f32_16x16x32_bf16(A, B1, acc1, 0, 0, 0);
    acc2 = __builtin_amdgcn_mfma_f32_16x16x32_bf16(A, B2, acc2, 0, 0, 0);
    acc3 = __builtin_amdgcn_mfma_f32_16x16x32_bf16(A, B3, acc3, 0, 0, 0);
    if (w == 3)
      accA = __builtin_amdgcn_mfma_f32_16x16x32_bf16(A, BA, accA, 0, 0, 0);
  }

  const int b     = row0 >> 9;
  const int node0 = (row0 & 511) + quad * 4;
  f32x4 accs[4] = {acc0, acc1, acc2, acc3};
  #pragma unroll
  for (int ft = 0; ft < 4; ++ft) {
    const int f = w * 64 + ft * 16 + nn;
    uint2 o;
    o.x = pk2f(accs[ft][0], accs[ft][1]);
    o.y = pk2f(accs[ft][2], accs[ft][3]);
    *(uint2*)(WhT + (size_t)((b * 8 + (f >> 5)) * 32 + (f & 31)) * 512 + node0) = o;
  }
  if (w == 3) {
    float4 sv;
    sv.x = accA[0] * L2E; sv.y = accA[1] * L2E;
    sv.z = accA[2] * L2E; sv.w = accA[3] * L2E;
    float* dst = (nn < 8) ? (s1T + (size_t)(b * 8 + nn) * 512 + node0)
                          : (s2T + (size_t)(b * 8 + (nn - 8)) * 512 + node0);
    *(float4*)dst = sv;
  }
}

// ---------------- k_attn (r8 passing version, byte-identical) ----------------
__global__ __launch_bounds__(512, 2) void k_attn(
    const int* __restrict__ adj, const int* __restrict__ ety,
    const float* __restrict__ s1T, const float* __restrict__ s2T,
    const unsigned short* __restrict__ WhT, const float* __restrict__ emb,
    const float* __restrict__ gam, const float* __restrict__ bet,
    float* __restrict__ out)
{
  __shared__ float2 lnS[16 * 4];
  __shared__ float  s2S[8 * 512];
  __shared__ float  redS[256 * 18];
  __shared__ alignas(16) unsigned int codesS[16 * 132];   // 528 B row stride

  const int t    = threadIdx.x;
  const int b    = blockIdx.x >> 5;
  const int i0   = (blockIdx.x & 31) * 16;
  const int W    = t >> 6;
  const int w    = W & 3;
  const int jh   = W >> 2;
  const int L    = t & 63;
  const int i    = L & 15;
  const int quad = L >> 4;
  const int h0   = w, h1 = w + 4;

  {
    const float4* sg = (const float4*)(s2T + (size_t)b * 8 * 512);
    float4* ss = (float4*)s2S;
    ss[t]       = sg[t];
    ss[t + 512] = sg[t + 512];
  }
  { // fused pack: adj/ety slice -> codesS
    const int r = t >> 5, c = t & 31;
    const size_t base = ((size_t)(b * NN + i0 + r) << 9) + c * 16;
    const int4* ap = (const int4*)(adj + base);
    const int4* ep = (const int4*)(ety + base);
    unsigned o[4];
    #pragma unroll
    for (int g = 0; g < 4; ++g) {
      const int4 a = ap[g];
      const int4 e = ep[g];
      o[g] = (unsigned)(e.x | (a.x << 6))
           | ((unsigned)(e.y | (a.y << 6)) << 8)
           | ((unsigned)(e.z | (a.z << 6)) << 16)
           | ((unsigned)(e.w | (a.w << 6)) << 24);
    }
    uint4 v; v.x = o[0]; v.y = o[1]; v.z = o[2]; v.w = o[3];
    *(uint4*)&codesS[r * 132 + c * 4] = v;
  }

  // register-resident emb table: lane L holds entry for type==L (L<50), per head pair
  float tabx = 0.f, taby = 0.f;
  if (L < NE) {
    tabx = emb[L * H + h0] * L2E + RBIAS;
    taby = emb[L * H + h1] * L2E + RBIAS;
  }
  const int txi = __builtin_bit_cast(int, tabx);
  const int tyi = __builtin_bit_cast(int, taby);

  const int row   = b * NN + i0 + i;
  const int jbase = jh * 256;
  const float si0 = s1T[(size_t)(b * 8 + h0) * 512 + i0 + i];
  const float si1 = s1T[(size_t)(b * 8 + h1) * 512 + i0 + i];
  const unsigned short* wt00 = WhT + (size_t)((b * 8 + h0) * 32 + i)      * 512;
  const unsigned short* wt01 = WhT + (size_t)((b * 8 + h0) * 32 + 16 + i) * 512;
  const unsigned short* wt10 = WhT + (size_t)((b * 8 + h1) * 32 + i)      * 512;
  const unsigned short* wt11 = WhT + (size_t)((b * 8 + h1) * 32 + 16 + i) * 512;

  f32x4 acc00 = {0.f,0.f,0.f,0.f}, acc01 = {0.f,0.f,0.f,0.f};
  f32x4 acc10 = {0.f,0.f,0.f,0.f}, acc11 = {0.f,0.f,0.f,0.f};
  f32x4 accL0 = {0.f,0.f,0.f,0.f}, accL1 = {0.f,0.f,0.f,0.f};
  const short one_bf = (short)0x3F80;
  const short8 ONES = {one_bf, one_bf, one_bf, one_bf, one_bf, one_bf, one_bf, one_bf};

  const float*  s2p0 = s2S + h0 * 512;
  const float*  s2p1 = s2S + h1 * 512;

  // A-frag pipeline: kc=0
  const int ja0 = jbase + quad * 8;
  short8 nA00 = *(const short8*)(wt00 + ja0);
  short8 nA01 = *(const short8*)(wt01 + ja0);
  short8 nA10 = *(const short8*)(wt10 + ja0);
  short8 nA11 = *(const short8*)(wt11 + ja0);

  __syncthreads();

  // codes for this thread's (i, jh, quad) from LDS (2-way bank = free)
  uint2 cw[8];
  {
    const unsigned int* cwp = &codesS[i * 132 + (jbase >> 2) + quad * 2];
    #pragma unroll
    for (int kc = 0; kc < 8; ++kc) {
      cw[kc].x = cwp[kc * 8];
      cw[kc].y = cwp[kc * 8 + 1];
    }
  }

  // e-operand pipeline: stage kc=0
  float2 em[8]; float4 sa0, sb0, sa1, sb1;
  {
    sa0 = *(const float4*)&s2p0[ja0];
    sb0 = *(const float4*)&s2p0[ja0 + 4];
    sa1 = *(const float4*)&s2p1[ja0];
    sb1 = *(const float4*)&s2p1[ja0 + 4];
    #pragma unroll
    for (int q = 0; q < 8; ++q) {
      const unsigned cword = (q < 4) ? cw[0].x : cw[0].y;
      const unsigned cb = (cword >> ((q & 3) * 8)) & 0xffu;
      const int ad = (int)((cb & 0x3fu) << 2);
      const float gx = __builtin_bit_cast(float, __builtin_amdgcn_ds_bpermute(ad, txi));
      const float gy = __builtin_bit_cast(float, __builtin_amdgcn_ds_bpermute(ad, tyi));
      em[q].x = (cb >= 64u) ? gx : MASKB;
      em[q].y = (cb >= 64u) ? gy : MASKB;
    }
  }

  #pragma unroll
  for (int kc = 0; kc < 8; ++kc) {
    const int ja = jbase + kc * 32 + quad * 8;
    const short8 A00 = nA00, A01 = nA01, A10 = nA10, A11 = nA11;
    { // prefetch next A-frags (last-iter overread stays inside d_ws)
      const int jn = ja + 32;
      nA00 = *(const short8*)(wt00 + jn);
      nA01 = *(const short8*)(wt01 + jn);
      nA10 = *(const short8*)(wt10 + jn);
      nA11 = *(const short8*)(wt11 + jn);
    }
    // issue next iteration's LDS/crossbar operands NOW
    float2 emn[8]; float4 na0, nb0, na1, nb1;
    if (kc < 7) {
      const int jx = ja + 32;
      na0 = *(const float4*)&s2p0[jx];
      nb0 = *(const float4*)&s2p0[jx + 4];
      na1 = *(const float4*)&s2p1[jx];
      nb1 = *(const float4*)&s2p1[jx + 4];
      #pragma unroll
      for (int q = 0; q < 8; ++q) {
        const unsigned cword = (q < 4) ? cw[kc + 1].x : cw[kc + 1].y;
        const unsigned cb = (cword >> ((q & 3) * 8)) & 0xffu;
        const int ad = (int)((cb & 0x3fu) << 2);
        const float gx = __builtin_bit_cast(float, __builtin_amdgcn_ds_bpermute(ad, txi));
        const float gy = __builtin_bit_cast(float, __builtin_amdgcn_ds_bpermute(ad, tyi));
        emn[q].x = (cb >= 64u) ? gx : MASKB;
        emn[q].y = (cb >= 64u) ? gy : MASKB;
      }
    }

    const float s20[8] = {sa0.x, sa0.y, sa0.z, sa0.w, sb0.x, sb0.y, sb0.z, sb0.w};
    const float s21[8] = {sa1.x, sa1.y, sa1.z, sa1.w, sb1.x, sb1.y, sb1.z, sb1.w};
    unsigned u0[8], u1[8];
    #pragma unroll
    for (int q = 0; q < 8; ++q) {
      float e0 = si0 + s20[q] + em[q].x;
      float e1 = si1 + s21[q] + em[q].y;
      e0 = fmaxf(e0, 0.2f * e0);
      e1 = fmaxf(e1, 0.2f * e1);
      u0[q] = __float_as_uint(exp2f(e0));
      u1[q] = __float_as_uint(exp2f(e1));
    }
    uint4 U0, U1;
    U0.x = pk_bf16(u0[0], u0[1]); U0.y = pk_bf16(u0[2], u0[3]);
    U0.z = pk_bf16(u0[4], u0[5]); U0.w = pk_bf16(u0[6], u0[7]);
    U1.x = pk_bf16(u1[0], u1[1]); U1.y = pk_bf16(u1[2], u1[3]);
    U1.z = pk_bf16(u1[4], u1[5]); U1.w = pk_bf16(u1[6], u1[7]);
    const short8 B0 = __builtin_bit_cast(short8, U0);
    const short8 B1 = __builtin_bit_cast(short8, U1);

    acc00 = __builtin_amdgcn_mfma_f32_16x16x32_bf16(A00, B0, acc00, 0, 0, 0);
    acc01 = __builtin_amdgcn_mfma_f32_16x16x32_bf16(A01, B0, acc01, 0, 0, 0);
    acc10 = __builtin_amdgcn_mfma_f32_16x16x32_bf16(A10, B1, acc10, 0, 0, 0);
    acc11 = __builtin_amdgcn_mfma_f32_16x16x32_bf16(A11, B1, acc11, 0, 0, 0);
    accL0 = __builtin_amdgcn_mfma_f32_16x16x32_bf16(ONES, B0, accL0, 0, 0, 0);
    accL1 = __builtin_amdgcn_mfma_f32_16x16x32_bf16(ONES, B1, accL1, 0, 0, 0);

    if (kc < 7) {
      sa0 = na0; sb0 = nb0; sa1 = na1; sb1 = nb1;
      #pragma unroll
      for (int q = 0; q < 8; ++q) em[q] = emn[q];
    }
  }

  const float l0 = accL0[0];   // D[m][i] = l_i for every m
  const float l1 = accL1[0];

  const int tt = (w << 6) | L;
  if (jh == 1) {
    float* rp = redS + tt * 18;
    rp[0]=acc00[0]; rp[1]=acc00[1]; rp[2]=acc00[2]; rp[3]=acc00[3];
    rp[4]=acc01[0]; rp[5]=acc01[1]; rp[6]=acc01[2]; rp[7]=acc01[3];
    rp[8]=acc10[0]; rp[9]=acc10[1]; rp[10]=acc10[2]; rp[11]=acc10[3];
    rp[12]=acc11[0]; rp[13]=acc11[1]; rp[14]=acc11[2]; rp[15]=acc11[3];
    rp[16]=l0; rp[17]=l1;
  }
  __syncthreads();

  float vals[16]; float mu, rstd;
  if (jh == 0) {
    const float* rp = redS + tt * 18;
    acc00[0]+=rp[0]; acc00[1]+=rp[1]; acc00[2]+=rp[2]; acc00[3]+=rp[3];
    acc01[0]+=rp[4]; acc01[1]+=rp[5]; acc01[2]+=rp[6]; acc01[3]+=rp[7];
    acc10[0]+=rp[8]; acc10[1]+=rp[9]; acc10[2]+=rp[10]; acc10[3]+=rp[11];
    acc11[0]+=rp[12]; acc11[1]+=rp[13]; acc11[2]+=rp[14]; acc11[3]+=rp[15];
    const float inv0 = __builtin_amdgcn_rcpf(l0 + rp[16]);
    const float inv1 = __builtin_amdgcn_rcpf(l1 + rp[17]);
    #pragma unroll
    for (int r = 0; r < 4; ++r) {
      vals[r]      = acc00[r] * inv0;
      vals[4 + r]  = acc01[r] * inv0;
      vals[8 + r]  = acc10[r] * inv1;
      vals[12 + r] = acc11[r] * inv1;
    }
    float s = 0.f, ss = 0.f;
    #pragma unroll
    for (int k = 0; k < 16; ++k) { s += vals[k]; ss += vals[k] * vals[k]; }
    s += __shfl_xor(s, 16); ss += __shfl_xor(ss, 16);
    s += __shfl_xor(s, 32); ss += __shfl_xor(ss, 32);
    if (quad == 0) { float2 v; v.x = s; v.y = ss; lnS[i * 4 + w] = v; }
  }
  __syncthreads();
  if (jh == 1) return;
  {
    float S = 0.f, SS = 0.f;
    #pragma unroll
    for (int ww = 0; ww < 4; ++ww) { const float2 v = lnS[i * 4 + ww]; S += v.x; SS += v.y; }
    mu = S * (1.0f / 256.0f);
    const float var = SS * (1.0f / 256.0f) - mu * mu;
    rstd = rsqrtf(var + 1e-5f);
  }
  const int fb[4] = { h0 * 32 + quad * 4, h0 * 32 + 16 + quad * 4,
                      h1 * 32 + quad * 4, h1 * 32 + 16 + quad * 4 };
  #pragma unroll
  for (int g = 0; g < 4; ++g) {
    const float4 gv = *(const float4*)(gam + fb[g]);
    const float4 bv = *(const float4*)(bet + fb[g]);
    float4 o;
    o.x = (vals[g*4+0] - mu) * rstd * gv.x + bv.x;
    o.y = (vals[g*4+1] - mu) * rstd * gv.y + bv.y;
    o.z = (vals[g*4+2] - mu) * rstd * gv.z + bv.z;
    o.w = (vals[g*4+3] - mu) * rstd * gv.w + bv.w;
    o.x = o.x > 0.f ? o.x : exp2f(o.x * L2E) - 1.f;
    o.y = o.y > 0.f ? o.y : exp2f(o.y * L2E) - 1.f;
    o.z = o.z > 0.f ? o.z : exp2f(o.z * L2E) - 1.f;
    o.w = o.w > 0.f ? o.w : exp2f(o.w * L2E) - 1.f;
    *(float4*)(out + (size_t)row * FOUT + fb[g]) = o;
  }
}

extern "C" void kernel_launch(void* const* d_in, const int* in_sizes, int n_in,
                              void* d_out, int out_size, void* d_ws, size_t ws_size,
                              hipStream_t stream) {
  (void)in_sizes; (void)n_in; (void)out_size; (void)ws_size;
  const float* x   = (const float*)d_in[0];
  const int*   adj = (const int*)  d_in[1];
  const int*   ety = (const int*)  d_in[2];
  const float* Wm  = (const float*)d_in[3];
  const float* a1  = (const float*)d_in[4];
  const float* a2  = (const float*)d_in[5];
  const float* emb = (const float*)d_in[6];
  const float* gam = (const float*)d_in[7];
  const float* bet = (const float*)d_in[8];
  float* out = (float*)d_out;

  unsigned short* WhT  = (unsigned short*)d_ws;             // 16*8*32*512 bf16 = 4 MB
  unsigned short* WbTa = WhT + (size_t)NB * H * 32 * 512;   // 272*256 bf16
  float* s1T  = (float*)(WbTa + (size_t)272 * FIN);         // 16*8*512 fp32 (pre-scaled)
  float* s2T  = s1T + (size_t)NB * H * NN;                  // 16*8*512 fp32 (pre-scaled)

  k_prew<<<dim3(256), dim3(256), 0, stream>>>(Wm, a1, a2, WbTa);
  k_gp  <<<dim3(512), dim3(256), 0, stream>>>(x, WbTa, WhT, s1T, s2T);
  k_attn<<<dim3(NB * (NN / 16)), dim3(512), 0, stream>>>(adj, ety, s1T, s2T, WhT, emb, gam, bet, out);
}

// Round 11
// 124.092 us; speedup vs baseline: 1.5651x; 1.0156x over previous
//
#include <hip/hip_runtime.h>
#include <hip/hip_bf16.h>
#include <stdint.h>

namespace gat {
constexpr int NB   = 16;
constexpr int NN   = 512;
constexpr int FIN  = 256;
constexpr int FOUT = 256;
constexpr int H    = 8;
constexpr int NE   = 50;
constexpr float L2E  = 1.4426950408889634f;   // log2(e)
constexpr float MASKB = -192.0f;              // masked emb entry: exp2 -> ~5e-11
constexpr float RBIAS = 0.00281502f;          // counters bf16-truncation bias
}
using namespace gat;

typedef __attribute__((ext_vector_type(8))) short short8;
typedef __attribute__((ext_vector_type(4))) float f32x4;

__device__ __forceinline__ unsigned pk_bf16(unsigned ulo, unsigned uhi) {
  return __builtin_amdgcn_perm(uhi, ulo, 0x07060302u);   // take high halves (truncate)
}
__device__ __forceinline__ unsigned pk2f(float a, float b) {
  return pk_bf16(__float_as_uint(a) + 0x8000u, __float_as_uint(b) + 0x8000u);
}
__device__ __forceinline__ unsigned short bf1(float a) {
  return (unsigned short)((__float_as_uint(a) + 0x8000u) >> 16);
}

// ---------------- k_prew v2: straggler-free (256 blocks) — r8 verbatim ----------------
__global__ __launch_bounds__(256) void k_prew(const float* __restrict__ Wm,
                                              const float* __restrict__ a1,
                                              const float* __restrict__ a2,
                                              unsigned short* __restrict__ WbTa) {
  const int k = blockIdx.x;
  const int t = threadIdx.x;
  const float* wr = Wm + (size_t)k * FOUT;
  WbTa[t * FIN + k] = bf1(wr[t]);
  if (t < H) {
    const int h = t;
    float v1 = 0.f, v2 = 0.f;
    #pragma unroll
    for (int d = 0; d < 32; ++d) {
      const float wv = wr[h * 32 + d];
      v1 += wv * a1[d];
      v2 += wv * a2[d];
    }
    WbTa[(256 + h) * FIN + k] = bf1(v1);
    WbTa[(264 + h) * FIN + k] = bf1(v2);
  }
}

// ------------- k_gp v3: r9 body + XCD-locality remap (b = blk & 15) -------------
// Same-b blocks land on the same XCD (round-robin dispatch, b%8 constant per b), so the
// WhT/s1T/s2T slices this kernel writes stay dirty in ONE XCD's L2 — exactly where
// k_attn's same-b blocks (same remap) read them. Removes the cross-XCD round-trip on
// 128 MB of redundant WhT reads.
__global__ __launch_bounds__(256, 2) void k_gp(
    const float* __restrict__ x, const unsigned short* __restrict__ WbTa,
    unsigned short* __restrict__ WhT, float* __restrict__ s1T, float* __restrict__ s2T)
{
  const int t = threadIdx.x;

  __shared__ alignas(16) unsigned short xS[16 * 264];
  const int row0 = ((blockIdx.x & 15) << 9) + ((blockIdx.x >> 4) << 4);  // b-major remap
  {
    const int r  = t >> 4;
    const int kb = (t & 15) * 16;
    const float4* xg = (const float4*)(x + (size_t)(row0 + r) * FIN + kb);
    const float4 v0 = xg[0], v1 = xg[1], v2 = xg[2], v3 = xg[3];
    uint4 o0, o1;
    o0.x = pk2f(v0.x, v0.y); o0.y = pk2f(v0.z, v0.w);
    o0.z = pk2f(v1.x, v1.y); o0.w = pk2f(v1.z, v1.w);
    o1.x = pk2f(v2.x, v2.y); o1.y = pk2f(v2.z, v2.w);
    o1.z = pk2f(v3.x, v3.y); o1.w = pk2f(v3.z, v3.w);
    *(uint4*)&xS[r * 264 + kb]     = o0;
    *(uint4*)&xS[r * 264 + kb + 8] = o1;
  }

  const int w    = t >> 6;
  const int L    = t & 63;
  const int nn   = L & 15;
  const int quad = L >> 4;
  const unsigned short* wb = WbTa + (size_t)(w * 64 + nn) * FIN + quad * 8;
  const unsigned short* wa = WbTa + (size_t)(256 + nn) * FIN + quad * 8;
  const unsigned short* xp = &xS[nn * 264 + quad * 8];

  // prefetch kc=0 B-fragments (global; issued before the staging barrier)
  short8 nB0 = *(const short8*)(wb);
  short8 nB1 = *(const short8*)(wb + 16 * FIN);
  short8 nB2 = *(const short8*)(wb + 32 * FIN);
  short8 nB3 = *(const short8*)(wb + 48 * FIN);
  short8 nBA = {};
  if (w == 3) nBA = *(const short8*)(wa);

  __syncthreads();

  f32x4 acc0 = {0.f,0.f,0.f,0.f}, acc1 = {0.f,0.f,0.f,0.f};
  f32x4 acc2 = {0.f,0.f,0.f,0.f}, acc3 = {0.f,0.f,0.f,0.f};
  f32x4 accA = {0.f,0.f,0.f,0.f};

  #pragma unroll
  for (int kc = 0; kc < 8; ++kc) {
    const int k0 = kc * 32;
    const short8 A  = *(const short8*)(xp + k0);   // LDS, fast
    const short8 B0 = nB0, B1 = nB1, B2 = nB2, B3 = nB3, BA = nBA;
    if (kc < 7) {   // issue next kc's B-fragments NOW (latency hides under MFMAs)
      const int kn = k0 + 32;
      nB0 = *(const short8*)(wb + kn);
      nB1 = *(const short8*)(wb + 16 * FIN + kn);
      nB2 = *(const short8*)(wb + 32 * FIN + kn);
      nB3 = *(const short8*)(wb + 48 * FIN + kn);
      if (w == 3) nBA = *(const short8*)(wa + kn);
    }
    acc0 = __builtin_amdgcn_mfma_f32_16x16x32_bf16(A, B0, acc0, 0, 0, 0);
    acc1 = __builtin_amdgcn_mfma_f32_16x16x32_bf16(A, B1, acc1, 0, 0, 0);
    acc2 = __builtin_amdgcn_mfma_f32_16x16x32_bf16(A, B2, acc2, 0, 0, 0);
    acc3 = __builtin_amdgcn_mfma_f32_16x16x32_bf16(A, B3, acc3, 0, 0, 0);
    if (w == 3)
      accA = __builtin_amdgcn_mfma_f32_16x16x32_bf16(A, BA, accA, 0, 0, 0);
  }

  const int b     = row0 >> 9;
  const int node0 = (row0 & 511) + quad * 4;
  f32x4 accs[4] = {acc0, acc1, acc2, acc3};
  #pragma unroll
  for (int ft = 0; ft < 4; ++ft) {
    const int f = w * 64 + ft * 16 + nn;
    uint2 o;
    o.x = pk2f(accs[ft][0], accs[ft][1]);
    o.y = pk2f(accs[ft][2], accs[ft][3]);
    *(uint2*)(WhT + (size_t)((b * 8 + (f >> 5)) * 32 + (f & 31)) * 512 + node0) = o;
  }
  if (w == 3) {
    float4 sv;
    sv.x = accA[0] * L2E; sv.y = accA[1] * L2E;
    sv.z = accA[2] * L2E; sv.w = accA[3] * L2E;
    float* dst = (nn < 8) ? (s1T + (size_t)(b * 8 + nn) * 512 + node0)
                          : (s2T + (size_t)(b * 8 + (nn - 8)) * 512 + node0);
    *(float4*)dst = sv;
  }
}

// ------------- k_attn v4: r9 body + XCD-locality remap (b = blk & 15) -------------
// All 32 blocks of batch b share one XCD; each reads the FULL 256 KB WhT b-slice
// (A-frags are i0-independent), which the same-XCD k_gp blocks just wrote -> L2 hits
// instead of 128 MB of chip-wide cross-XCD traffic.
__global__ __launch_bounds__(512, 2) void k_attn(
    const int* __restrict__ adj, const int* __restrict__ ety,
    const float* __restrict__ s1T, const float* __restrict__ s2T,
    const unsigned short* __restrict__ WhT, const float* __restrict__ emb,
    const float* __restrict__ gam, const float* __restrict__ bet,
    float* __restrict__ out)
{
  __shared__ float2 lnS[16 * 4];
  __shared__ float  s2S[8 * 512];
  __shared__ float  redS[256 * 18];
  __shared__ alignas(16) unsigned int codesS[16 * 132];   // 528 B row stride

  const int t    = threadIdx.x;
  const int b    = blockIdx.x & 15;                 // b-major remap (same XCD as k_gp's b)
  const int i0   = ((blockIdx.x >> 4) & 31) * 16;
  const int W    = t >> 6;
  const int w    = W & 3;
  const int jh   = W >> 2;
  const int L    = t & 63;
  const int i    = L & 15;
  const int quad = L >> 4;
  const int h0   = w, h1 = w + 4;

  {
    const float4* sg = (const float4*)(s2T + (size_t)b * 8 * 512);
    float4* ss = (float4*)s2S;
    ss[t]       = sg[t];
    ss[t + 512] = sg[t + 512];
  }
  { // fused pack: adj/ety slice -> codesS
    const int r = t >> 5, c = t & 31;
    const size_t base = ((size_t)(b * NN + i0 + r) << 9) + c * 16;
    const int4* ap = (const int4*)(adj + base);
    const int4* ep = (const int4*)(ety + base);
    unsigned o[4];
    #pragma unroll
    for (int g = 0; g < 4; ++g) {
      const int4 a = ap[g];
      const int4 e = ep[g];
      o[g] = (unsigned)(e.x | (a.x << 6))
           | ((unsigned)(e.y | (a.y << 6)) << 8)
           | ((unsigned)(e.z | (a.z << 6)) << 16)
           | ((unsigned)(e.w | (a.w << 6)) << 24);
    }
    uint4 v; v.x = o[0]; v.y = o[1]; v.z = o[2]; v.w = o[3];
    *(uint4*)&codesS[r * 132 + c * 4] = v;
  }

  // register-resident emb table: lane L holds entry for type==L (L<50), per head pair
  float tabx = 0.f, taby = 0.f;
  if (L < NE) {
    tabx = emb[L * H + h0] * L2E + RBIAS;
    taby = emb[L * H + h1] * L2E + RBIAS;
  }
  const int txi = __builtin_bit_cast(int, tabx);
  const int tyi = __builtin_bit_cast(int, taby);

  const int row   = b * NN + i0 + i;
  const int jbase = jh * 256;
  const float si0 = s1T[(size_t)(b * 8 + h0) * 512 + i0 + i];
  const float si1 = s1T[(size_t)(b * 8 + h1) * 512 + i0 + i];
  const unsigned short* wt00 = WhT + (size_t)((b * 8 + h0) * 32 + i)      * 512;
  const unsigned short* wt01 = WhT + (size_t)((b * 8 + h0) * 32 + 16 + i) * 512;
  const unsigned short* wt10 = WhT + (size_t)((b * 8 + h1) * 32 + i)      * 512;
  const unsigned short* wt11 = WhT + (size_t)((b * 8 + h1) * 32 + 16 + i) * 512;

  f32x4 acc00 = {0.f,0.f,0.f,0.f}, acc01 = {0.f,0.f,0.f,0.f};
  f32x4 acc10 = {0.f,0.f,0.f,0.f}, acc11 = {0.f,0.f,0.f,0.f};
  f32x4 accL0 = {0.f,0.f,0.f,0.f}, accL1 = {0.f,0.f,0.f,0.f};
  const short one_bf = (short)0x3F80;
  const short8 ONES = {one_bf, one_bf, one_bf, one_bf, one_bf, one_bf, one_bf, one_bf};

  const float*  s2p0 = s2S + h0 * 512;
  const float*  s2p1 = s2S + h1 * 512;

  // A-frag pipeline: kc=0
  const int ja0 = jbase + quad * 8;
  short8 nA00 = *(const short8*)(wt00 + ja0);
  short8 nA01 = *(const short8*)(wt01 + ja0);
  short8 nA10 = *(const short8*)(wt10 + ja0);
  short8 nA11 = *(const short8*)(wt11 + ja0);

  __syncthreads();

  // codes for this thread's (i, jh, quad) from LDS (2-way bank = free)
  uint2 cw[8];
  {
    const unsigned int* cwp = &codesS[i * 132 + (jbase >> 2) + quad * 2];
    #pragma unroll
    for (int kc = 0; kc < 8; ++kc) {
      cw[kc].x = cwp[kc * 8];
      cw[kc].y = cwp[kc * 8 + 1];
    }
  }

  // e-operand pipeline: stage kc=0
  float2 em[8]; float4 sa0, sb0, sa1, sb1;
  {
    sa0 = *(const float4*)&s2p0[ja0];
    sb0 = *(const float4*)&s2p0[ja0 + 4];
    sa1 = *(const float4*)&s2p1[ja0];
    sb1 = *(const float4*)&s2p1[ja0 + 4];
    #pragma unroll
    for (int q = 0; q < 8; ++q) {
      const unsigned cword = (q < 4) ? cw[0].x : cw[0].y;
      const unsigned cb = (cword >> ((q & 3) * 8)) & 0xffu;
      const int ad = (int)((cb & 0x3fu) << 2);
      const float gx = __builtin_bit_cast(float, __builtin_amdgcn_ds_bpermute(ad, txi));
      const float gy = __builtin_bit_cast(float, __builtin_amdgcn_ds_bpermute(ad, tyi));
      em[q].x = (cb >= 64u) ? gx : MASKB;
      em[q].y = (cb >= 64u) ? gy : MASKB;
    }
  }

  #pragma unroll
  for (int kc = 0; kc < 8; ++kc) {
    const int ja = jbase + kc * 32 + quad * 8;
    const short8 A00 = nA00, A01 = nA01, A10 = nA10, A11 = nA11;
    { // prefetch next A-frags (last-iter overread stays inside d_ws)
      const int jn = ja + 32;
      nA00 = *(const short8*)(wt00 + jn);
      nA01 = *(const short8*)(wt01 + jn);
      nA10 = *(const short8*)(wt10 + jn);
      nA11 = *(const short8*)(wt11 + jn);
    }
    // issue next iteration's LDS/crossbar operands NOW
    float2 emn[8]; float4 na0, nb0, na1, nb1;
    if (kc < 7) {
      const int jx = ja + 32;
      na0 = *(const float4*)&s2p0[jx];
      nb0 = *(const float4*)&s2p0[jx + 4];
      na1 = *(const float4*)&s2p1[jx];
      nb1 = *(const float4*)&s2p1[jx + 4];
      #pragma unroll
      for (int q = 0; q < 8; ++q) {
        const unsigned cword = (q < 4) ? cw[kc + 1].x : cw[kc + 1].y;
        const unsigned cb = (cword >> ((q & 3) * 8)) & 0xffu;
        const int ad = (int)((cb & 0x3fu) << 2);
        const float gx = __builtin_bit_cast(float, __builtin_amdgcn_ds_bpermute(ad, txi));
        const float gy = __builtin_bit_cast(float, __builtin_amdgcn_ds_bpermute(ad, tyi));
        emn[q].x = (cb >= 64u) ? gx : MASKB;
        emn[q].y = (cb >= 64u) ? gy : MASKB;
      }
    }

    const float s20[8] = {sa0.x, sa0.y, sa0.z, sa0.w, sb0.x, sb0.y, sb0.z, sb0.w};
    const float s21[8] = {sa1.x, sa1.y, sa1.z, sa1.w, sb1.x, sb1.y, sb1.z, sb1.w};
    unsigned u0[8], u1[8];
    #pragma unroll
    for (int q = 0; q < 8; ++q) {
      float e0 = si0 + s20[q] + em[q].x;
      float e1 = si1 + s21[q] + em[q].y;
      e0 = fmaxf(e0, 0.2f * e0);
      e1 = fmaxf(e1, 0.2f * e1);
      u0[q] = __float_as_uint(exp2f(e0));
      u1[q] = __float_as_uint(exp2f(e1));
    }
    uint4 U0, U1;
    U0.x = pk_bf16(u0[0], u0[1]); U0.y = pk_bf16(u0[2], u0[3]);
    U0.z = pk_bf16(u0[4], u0[5]); U0.w = pk_bf16(u0[6], u0[7]);
    U1.x = pk_bf16(u1[0], u1[1]); U1.y = pk_bf16(u1[2], u1[3]);
    U1.z = pk_bf16(u1[4], u1[5]); U1.w = pk_bf16(u1[6], u1[7]);
    const short8 B0 = __builtin_bit_cast(short8, U0);
    const short8 B1 = __builtin_bit_cast(short8, U1);

    acc00 = __builtin_amdgcn_mfma_f32_16x16x32_bf16(A00, B0, acc00, 0, 0, 0);
    acc01 = __builtin_amdgcn_mfma_f32_16x16x32_bf16(A01, B0, acc01, 0, 0, 0);
    acc10 = __builtin_amdgcn_mfma_f32_16x16x32_bf16(A10, B1, acc10, 0, 0, 0);
    acc11 = __builtin_amdgcn_mfma_f32_16x16x32_bf16(A11, B1, acc11, 0, 0, 0);
    accL0 = __builtin_amdgcn_mfma_f32_16x16x32_bf16(ONES, B0, accL0, 0, 0, 0);
    accL1 = __builtin_amdgcn_mfma_f32_16x16x32_bf16(ONES, B1, accL1, 0, 0, 0);

    if (kc < 7) {
      sa0 = na0; sb0 = nb0; sa1 = na1; sb1 = nb1;
      #pragma unroll
      for (int q = 0; q < 8; ++q) em[q] = emn[q];
    }
  }

  const float l0 = accL0[0];   // D[m][i] = l_i for every m
  const float l1 = accL1[0];

  const int tt = (w << 6) | L;
  if (jh == 1) {
    float* rp = redS + tt * 18;
    rp[0]=acc00[0]; rp[1]=acc00[1]; rp[2]=acc00[2]; rp[3]=acc00[3];
    rp[4]=acc01[0]; rp[5]=acc01[1]; rp[6]=acc01[2]; rp[7]=acc01[3];
    rp[8]=acc10[0]; rp[9]=acc10[1]; rp[10]=acc10[2]; rp[11]=acc10[3];
    rp[12]=acc11[0]; rp[13]=acc11[1]; rp[14]=acc11[2]; rp[15]=acc11[3];
    rp[16]=l0; rp[17]=l1;
  }
  __syncthreads();

  float vals[16]; float mu, rstd;
  if (jh == 0) {
    const float* rp = redS + tt * 18;
    acc00[0]+=rp[0]; acc00[1]+=rp[1]; acc00[2]+=rp[2]; acc00[3]+=rp[3];
    acc01[0]+=rp[4]; acc01[1]+=rp[5]; acc01[2]+=rp[6]; acc01[3]+=rp[7];
    acc10[0]+=rp[8]; acc10[1]+=rp[9]; acc10[2]+=rp[10]; acc10[3]+=rp[11];
    acc11[0]+=rp[12]; acc11[1]+=rp[13]; acc11[2]+=rp[14]; acc11[3]+=rp[15];
    const float inv0 = __builtin_amdgcn_rcpf(l0 + rp[16]);
    const float inv1 = __builtin_amdgcn_rcpf(l1 + rp[17]);
    #pragma unroll
    for (int r = 0; r < 4; ++r) {
      vals[r]      = acc00[r] * inv0;
      vals[4 + r]  = acc01[r] * inv0;
      vals[8 + r]  = acc10[r] * inv1;
      vals[12 + r] = acc11[r] * inv1;
    }
    float s = 0.f, ss = 0.f;
    #pragma unroll
    for (int k = 0; k < 16; ++k) { s += vals[k]; ss += vals[k] * vals[k]; }
    s += __shfl_xor(s, 16); ss += __shfl_xor(ss, 16);
    s += __shfl_xor(s, 32); ss += __shfl_xor(ss, 32);
    if (quad == 0) { float2 v; v.x = s; v.y = ss; lnS[i * 4 + w] = v; }
  }
  __syncthreads();
  if (jh == 1) return;
  {
    float S = 0.f, SS = 0.f;
    #pragma unroll
    for (int ww = 0; ww < 4; ++ww) { const float2 v = lnS[i * 4 + ww]; S += v.x; SS += v.y; }
    mu = S * (1.0f / 256.0f);
    const float var = SS * (1.0f / 256.0f) - mu * mu;
    rstd = rsqrtf(var + 1e-5f);
  }
  const int fb[4] = { h0 * 32 + quad * 4, h0 * 32 + 16 + quad * 4,
                      h1 * 32 + quad * 4, h1 * 32 + 16 + quad * 4 };
  #pragma unroll
  for (int g = 0; g < 4; ++g) {
    const float4 gv = *(const float4*)(gam + fb[g]);
    const float4 bv = *(const float4*)(bet + fb[g]);
    float4 o;
    o.x = (vals[g*4+0] - mu) * rstd * gv.x + bv.x;
    o.y = (vals[g*4+1] - mu) * rstd * gv.y + bv.y;
    o.z = (vals[g*4+2] - mu) * rstd * gv.z + bv.z;
    o.w = (vals[g*4+3] - mu) * rstd * gv.w + bv.w;
    o.x = o.x > 0.f ? o.x : exp2f(o.x * L2E) - 1.f;
    o.y = o.y > 0.f ? o.y : exp2f(o.y * L2E) - 1.f;
    o.z = o.z > 0.f ? o.z : exp2f(o.z * L2E) - 1.f;
    o.w = o.w > 0.f ? o.w : exp2f(o.w * L2E) - 1.f;
    *(float4*)(out + (size_t)row * FOUT + fb[g]) = o;
  }
}

extern "C" void kernel_launch(void* const* d_in, const int* in_sizes, int n_in,
                              void* d_out, int out_size, void* d_ws, size_t ws_size,
                              hipStream_t stream) {
  (void)in_sizes; (void)n_in; (void)out_size; (void)ws_size;
  const float* x   = (const float*)d_in[0];
  const int*   adj = (const int*)  d_in[1];
  const int*   ety = (const int*)  d_in[2];
  const float* Wm  = (const float*)d_in[3];
  const float* a1  = (const float*)d_in[4];
  const float* a2  = (const float*)d_in[5];
  const float* emb = (const float*)d_in[6];
  const float* gam = (const float*)d_in[7];
  const float* bet = (const float*)d_in[8];
  float* out = (float*)d_out;

  unsigned short* WhT  = (unsigned short*)d_ws;             // 16*8*32*512 bf16 = 4 MB
  unsigned short* WbTa = WhT + (size_t)NB * H * 32 * 512;   // 272*256 bf16
  float* s1T  = (float*)(WbTa + (size_t)272 * FIN);         // 16*8*512 fp32 (pre-scaled)
  float* s2T  = s1T + (size_t)NB * H * NN;                  // 16*8*512 fp32 (pre-scaled)

  k_prew<<<dim3(256), dim3(256), 0, stream>>>(Wm, a1, a2, WbTa);
  k_gp  <<<dim3(512), dim3(256), 0, stream>>>(x, WbTa, WhT, s1T, s2T);
  k_attn<<<dim3(NB * (NN / 16)), dim3(512), 0, stream>>>(adj, ety, s1T, s2T, WhT, emb, gam, bet, out);
}